// Round 9
// baseline (130.801 us; speedup 1.0000x reference)
//
#include <hip/hip_runtime.h>
#include <hip/hip_bf16.h>

// PQ embedding gather:
//   out[t, m*32 + j] = centroids[m, item_codes[ids[t], m], j]
// B*S = 102400 tokens, M = 8 code bytes, SUB = 32 floats, 256 centroids/byte.
//   ids:       int32   [B*S]
//   item_codes:int32   [(N+1)*8]    (32 MB, random-row gather -> latency hazard)
//   centroids: float32 [8*256*32]   (256 KB)
//   out:       float32 [B*S*256]    (105 MB, streaming coalesced write)
//
// 64 tokens / 128-thread block (grid 1600, ~6 blocks/CU for barrier overlap).
//   Phase A: HBM->LDS direct DMA via global_load_lds width=16 (no VGPR
//            round-trip).  LDS byte offset = tid*16 = wave_base + lane*16,
//            satisfying the DMA's wave-uniform-base + lane*size constraint.
//            NOTE: address-space casts must be C-style (addrspacecast);
//            reinterpret_cast does not compile.
//   Phase B: each wave streams 32 tokens (1 KB each), unroll x8 independent
//            centroid-gather/store chains; plain cached stores (nt stores
//            regressed in R6).

typedef float f4 __attribute__((ext_vector_type(4)));
typedef const __attribute__((address_space(1))) void* gptr_t;
typedef __attribute__((address_space(3))) void* lptr_t;

#define M_BYTES 8
#define SUB_DIM 32
#define EMB     (M_BYTES * SUB_DIM)   // 256 floats per token
#define TOK_PER_BLOCK 64
#define BLOCK 128

__global__ __launch_bounds__(BLOCK) void ItemCodeLayer_30253749633338_kernel(
    const int*   __restrict__ ids,    // [B*S]
    const int*   __restrict__ codes,  // [(N+1)*M]
    const float* __restrict__ cent,   // [M*256*SUB]
    float*       __restrict__ out,    // [B*S*EMB]
    int n_tokens)
{
    __shared__ int s_codes[TOK_PER_BLOCK * M_BYTES];   // 2 KB, token-major

    const int tid  = threadIdx.x;
    const int base = blockIdx.x * TOK_PER_BLOCK;

    // ---- Phase A: 64 code rows -> LDS via direct DMA, one 16 B chunk/thread.
    {
        const int tA = tid >> 1;          // 0..63 : token within block
        const int h  = tid & 1;           // 0/1   : which 16 B half of the 32 B row
        int id = (base + tA < n_tokens) ? ids[base + tA] : 0;   // 2 lanes share line
        const int* gsrc = codes + (size_t)id * M_BYTES + h * 4;
        __builtin_amdgcn_global_load_lds(
            (gptr_t)gsrc,
            (lptr_t)&s_codes[tA * M_BYTES + h * 4],
            16, 0, 0);
    }
    __syncthreads();   // compiler drains vmcnt before s_barrier

    // ---- Phase B: each wave streams 32 tokens (1 KB per token), unroll x8.
    const int wave = tid >> 6;            // 0..1
    const int l    = tid & 63;
    const int lm   = l >> 3;              // code byte handled by this lane
    const int lj   = (l & 7) * 4;         // float offset within sub-embedding
    const float* centBase = cent + (size_t)lm * 256 * SUB_DIM + lj;

    #pragma unroll
    for (int it = 0; it < 32; it += 8) {
        int tk[8];
        f4  v[8];
        #pragma unroll
        for (int u = 0; u < 8; ++u) {
            tk[u] = wave * 32 + it + u;                  // 0..63, disjoint per wave
            int code = s_codes[tk[u] * M_BYTES + lm];    // LDS broadcast (8 lanes/addr)
            v[u] = *reinterpret_cast<const f4*>(centBase + (size_t)code * SUB_DIM);
        }
        #pragma unroll
        for (int u = 0; u < 8; ++u) {
            int t = base + tk[u];
            if (t < n_tokens) {
                // 64 lanes -> contiguous 1 KB cached store
                *reinterpret_cast<f4*>(
                    out + ((size_t)t * EMB + lm * SUB_DIM + lj)) = v[u];
            }
        }
    }
}

extern "C" void kernel_launch(void* const* d_in, const int* in_sizes, int n_in,
                              void* d_out, int out_size, void* d_ws, size_t ws_size,
                              hipStream_t stream) {
    const int*   ids   = (const int*)  d_in[0];   // input_ids  [B*S] int32
    const int*   codes = (const int*)  d_in[1];   // item_codes [(N+1)*M] int32
    const float* cent  = (const float*)d_in[2];   // centroids  [M*256*SUB] float32
    float*       out   = (float*)      d_out;

    const int n_tokens = in_sizes[0];             // 102400 tokens
    const int grid = (n_tokens + TOK_PER_BLOCK - 1) / TOK_PER_BLOCK;   // 1600

    hipLaunchKernelGGL(ItemCodeLayer_30253749633338_kernel,
                       dim3(grid), dim3(BLOCK), 0, stream,
                       ids, codes, cent, out, n_tokens);
}